// Round 1
// baseline (40492.191 us; speedup 1.0000x reference)
//
#include <hip/hip_runtime.h>
#include <math.h>

#define B_ 4
#define T_ 1024
#define D_ 1024
#define H_ 16
#define F_ 4096
#define L_ 8
#define NF_ 80
#define E_ 256
#define KW_ 128
#define G_ 16
#define CIN 416       // 2*NF + E
#define DH 64
#define M_ (B_*T_)    // 4096

__device__ __forceinline__ float gelu_f(float x) {
    return 0.5f * x * (1.0f + erff(x * 0.70710678118654752f));
}

// ---------------------------------------------------------------------------
// Generic GEMM: C[M,N] = act((A@W^T + bias) * post_scale) + resid, * rowmask
// A is (M,K) row-major (optionally split: first K1 cols from A, rest from A2),
// W is (N,K) row-major (all weights in this model are (out, in)).
// Tile: BM=64, BN=128, BK=16, 256 threads, 4x8 micro-tile per thread.
// ---------------------------------------------------------------------------
template<int ACT>  // 0 = none, 1 = exact GELU
__global__ __launch_bounds__(256)
void gemm_kernel(const float* __restrict__ A, const float* __restrict__ A2, int K1,
                 const float* __restrict__ W, const float* __restrict__ bias,
                 const float* __restrict__ resid, const float* __restrict__ rowmask,
                 float* __restrict__ C, int M, int N, int K, float post_scale)
{
    __shared__ float As[16][65];
    __shared__ float Ws[16][132];
    const int tid = threadIdx.x;
    const int tx = tid & 15;    // n-group: cols tx*4..+3 and 64+tx*4..+3
    const int ty = tid >> 4;    // m-group: rows ty*4..+3
    const int bm = blockIdx.y * 64;
    const int bn = blockIdx.x * 128;
    const int lda2 = K - K1;

    float acc[4][8];
#pragma unroll
    for (int i = 0; i < 4; ++i)
#pragma unroll
        for (int j = 0; j < 8; ++j) acc[i][j] = 0.f;

    for (int k0 = 0; k0 < K; k0 += 16) {
        // A tile: 64 rows x 16 k
#pragma unroll
        for (int l = 0; l < 4; ++l) {
            int e = tid + l * 256;
            int r = e >> 4, c = e & 15;
            int gm = bm + r, gk = k0 + c;
            float v = 0.f;
            if (gm < M && gk < K) {
                v = (gk < K1) ? A[(size_t)gm * K1 + gk]
                              : A2[(size_t)gm * lda2 + (gk - K1)];
            }
            As[c][r] = v;
        }
        // W tile: 128 rows x 16 k
#pragma unroll
        for (int l = 0; l < 8; ++l) {
            int e = tid + l * 256;
            int r = e >> 4, c = e & 15;
            int gn = bn + r, gk = k0 + c;
            float v = 0.f;
            if (gn < N && gk < K) v = W[(size_t)gn * K + gk];
            Ws[c][r] = v;
        }
        __syncthreads();
#pragma unroll
        for (int kk = 0; kk < 16; ++kk) {
            float a[4], b0[4], b1[4];
#pragma unroll
            for (int i = 0; i < 4; ++i) a[i] = As[kk][ty * 4 + i];
#pragma unroll
            for (int j = 0; j < 4; ++j) b0[j] = Ws[kk][tx * 4 + j];
#pragma unroll
            for (int j = 0; j < 4; ++j) b1[j] = Ws[kk][64 + tx * 4 + j];
#pragma unroll
            for (int i = 0; i < 4; ++i) {
#pragma unroll
                for (int j = 0; j < 4; ++j) acc[i][j]     += a[i] * b0[j];
#pragma unroll
                for (int j = 0; j < 4; ++j) acc[i][j + 4] += a[i] * b1[j];
            }
        }
        __syncthreads();
    }

#pragma unroll
    for (int i = 0; i < 4; ++i) {
        int gm = bm + ty * 4 + i;
        if (gm >= M) continue;
        float rm = rowmask ? rowmask[gm] : 1.f;
#pragma unroll
        for (int j = 0; j < 8; ++j) {
            int gn = bn + ((j < 4) ? (tx * 4 + j) : (64 + tx * 4 + (j - 4)));
            if (gn >= N) continue;
            float v = acc[i][j];
            if (bias) v += bias[gn];
            v *= post_scale;
            if (ACT == 1) v = gelu_f(v);
            if (resid) v += resid[(size_t)gm * N + gn];
            v *= rm;
            C[(size_t)gm * N + gn] = v;
        }
    }
}

// ---------------------------------------------------------------------------
// Build xin (M, 416) = [x | mu | embed[tokens]] per (b,t) row
// ---------------------------------------------------------------------------
__global__ __launch_bounds__(256)
void xin_kernel(const float* __restrict__ x, const float* __restrict__ mu,
                const int* __restrict__ tokens, const float* __restrict__ emb,
                float* __restrict__ xin)
{
    int m = blockIdx.x;
    int b = m >> 10, tt = m & 1023;
    int tok = tokens[m];
    for (int c = threadIdx.x; c < CIN; c += 256) {
        float v;
        if (c < NF_)            v = x[((size_t)b * NF_ + c) * T_ + tt];
        else if (c < 2 * NF_)   v = mu[((size_t)b * NF_ + (c - NF_)) * T_ + tt];
        else                    v = emb[(size_t)tok * E_ + (c - 2 * NF_)];
        xin[(size_t)m * CIN + c] = v;
    }
}

// ---------------------------------------------------------------------------
// h = (h + temb(t_b)) * y_mask ; temb = [sin(1000 t f_j), cos(1000 t f_j)]
// ---------------------------------------------------------------------------
__global__ __launch_bounds__(256)
void temb_kernel(float* __restrict__ h, const float* __restrict__ t,
                 const float* __restrict__ y_mask)
{
    int m = blockIdx.x;
    int b = m >> 10;
    int d = threadIdx.x * 4;
    float tb = t[b] * 1000.f;
    float rm = y_mask[m];
    float* p = h + (size_t)m * D_ + d;
    float4 v = *(const float4*)p;
    float out[4] = {v.x, v.y, v.z, v.w};
#pragma unroll
    for (int u = 0; u < 4; ++u) {
        int dd = d + u;
        int j = dd & 511;
        float fr = expf((float)j * (-9.210340371976184f / 511.f));
        float ang = tb * fr;
        float e = (dd < 512) ? sinf(ang) : cosf(ang);
        out[u] = (out[u] + e) * rm;
    }
    float4 o; o.x = out[0]; o.y = out[1]; o.z = out[2]; o.w = out[3];
    *(float4*)p = o;
}

// ---------------------------------------------------------------------------
// Transpose posconv weights (per depth) to wT[k][g][i][dl]
// src: posconv_w[dep][g*64+dl][i][k]  ((2, 1024, 64, 128))
// ---------------------------------------------------------------------------
__global__ __launch_bounds__(256)
void wtrans_kernel(const float* __restrict__ w, float* __restrict__ wT, int dep)
{
    int e = blockIdx.x * 256 + threadIdx.x;   // 128*16*64*64 = 8388608 total
    int dl = e & 63;
    int i  = (e >> 6) & 63;
    int g  = (e >> 12) & 15;
    int k  = e >> 16;
    wT[e] = w[(((size_t)dep * D_ + g * 64 + dl) * 64 + i) * KW_ + k];
}

// ---------------------------------------------------------------------------
// Grouped conv1d (K=128, pad 64/64, drop-last => out[t]=sum_k in[t+k-64]w[k])
// fused: hout = hin + gelu(conv + bias) * y_mask
// grid (T/128, G, B), 256 threads; LDS slab = group input slice (64ch x 255t)
// ---------------------------------------------------------------------------
__global__ __launch_bounds__(256)
void conv_kernel(const float* __restrict__ hin, float* __restrict__ hout,
                 const float* __restrict__ wT, const float* __restrict__ bias,
                 const float* __restrict__ y_mask)
{
    const int t0 = blockIdx.x * 128;
    const int g  = blockIdx.y;
    const int b  = blockIdx.z;
    const int tid = threadIdx.x;
    const int tx = tid & 15;    // d_local = tx*4 + c
    const int ty = tid >> 4;    // t_local = ty*8 + mm
    __shared__ float slab[64][256];   // [in_channel][time], 64 KiB

    for (int e = tid; e < 255 * 64; e += 256) {
        int ts = e >> 6, i = e & 63;
        int tg = t0 - 64 + ts;
        float v = 0.f;
        if (tg >= 0 && tg < T_) v = hin[(size_t)(b * T_ + tg) * D_ + g * 64 + i];
        slab[i][ts] = v;
    }
    __syncthreads();

    float acc[8][4];
#pragma unroll
    for (int mm = 0; mm < 8; ++mm)
#pragma unroll
        for (int c = 0; c < 4; ++c) acc[mm][c] = 0.f;

    for (int k = 0; k < KW_; ++k) {
        const float* wk = wT + ((size_t)k * G_ + g) * 4096;
#pragma unroll 4
        for (int i = 0; i < 64; ++i) {
            float4 wv = *(const float4*)(wk + i * 64 + tx * 4);
            float a[8];
#pragma unroll
            for (int mm = 0; mm < 8; ++mm) a[mm] = slab[i][ty * 8 + mm + k];
#pragma unroll
            for (int mm = 0; mm < 8; ++mm) {
                acc[mm][0] += a[mm] * wv.x;
                acc[mm][1] += a[mm] * wv.y;
                acc[mm][2] += a[mm] * wv.z;
                acc[mm][3] += a[mm] * wv.w;
            }
        }
    }

    int dl = tx * 4;
    float4 bb = *(const float4*)(bias + g * 64 + dl);
#pragma unroll
    for (int mm = 0; mm < 8; ++mm) {
        int tt = t0 + ty * 8 + mm;
        float rm = y_mask[b * T_ + tt];
        int ts = ty * 8 + mm + 64;
        float4 o;
        o.x = slab[dl + 0][ts] + gelu_f(acc[mm][0] + bb.x) * rm;
        o.y = slab[dl + 1][ts] + gelu_f(acc[mm][1] + bb.y) * rm;
        o.z = slab[dl + 2][ts] + gelu_f(acc[mm][2] + bb.z) * rm;
        o.w = slab[dl + 3][ts] + gelu_f(acc[mm][3] + bb.w) * rm;
        *(float4*)(hout + (size_t)(b * T_ + tt) * D_ + g * 64 + dl) = o;
    }
}

// ---------------------------------------------------------------------------
// LayerNorm over D (in-place), optional final rowmask multiply
// ---------------------------------------------------------------------------
__global__ __launch_bounds__(256)
void ln_kernel(float* __restrict__ X, const float* __restrict__ g,
               const float* __restrict__ bt, const float* __restrict__ rowmask)
{
    const int m = blockIdx.x;
    const int tid = threadIdx.x;
    const int d = tid * 4;
    float* p = X + (size_t)m * D_ + d;
    float4 v = *(const float4*)p;
    float s  = v.x + v.y + v.z + v.w;
    float s2 = v.x * v.x + v.y * v.y + v.z * v.z + v.w * v.w;
#pragma unroll
    for (int off = 32; off; off >>= 1) {
        s  += __shfl_down(s, off);
        s2 += __shfl_down(s2, off);
    }
    __shared__ float rs[4], rs2[4];
    int wid = tid >> 6;
    if ((tid & 63) == 0) { rs[wid] = s; rs2[wid] = s2; }
    __syncthreads();
    s  = rs[0] + rs[1] + rs[2] + rs[3];
    s2 = rs2[0] + rs2[1] + rs2[2] + rs2[3];
    float mean = s * (1.f / D_);
    float var  = s2 * (1.f / D_) - mean * mean;
    float inv  = rsqrtf(var + 1e-5f);
    float rm = rowmask ? rowmask[m] : 1.f;
    float4 gg = *(const float4*)(g + d);
    float4 bb = *(const float4*)(bt + d);
    float4 o;
    o.x = ((v.x - mean) * inv * gg.x + bb.x) * rm;
    o.y = ((v.y - mean) * inv * gg.y + bb.y) * rm;
    o.z = ((v.z - mean) * inv * gg.z + bb.z) * rm;
    o.w = ((v.w - mean) * inv * gg.w + bb.w) * rm;
    *(float4*)p = o;
}

// ---------------------------------------------------------------------------
// Flash attention, one wave per 64 queries of one (b,h).
// Q pre-scaled by Dh^-0.5 (GEMM post_scale). ALiBi + key-mask bias inline.
// ---------------------------------------------------------------------------
__global__ __launch_bounds__(64)
void attn_kernel(const float* __restrict__ Q, const float* __restrict__ Kb,
                 const float* __restrict__ Vb, const float* __restrict__ y_mask,
                 float* __restrict__ O)
{
    const int tid = threadIdx.x;
    const int qg = blockIdx.x * 64 + tid;
    const int h  = blockIdx.y;
    const int b  = blockIdx.z;
    const float slope = exp2f(-0.5f * (float)(h + 1));
    __shared__ float Ks[16][64];
    __shared__ float Vs[16][64];

    const float* qp = Q + ((size_t)(b * T_ + qg) * D_ + h * DH);
    float qr[64];
#pragma unroll
    for (int j = 0; j < 64; j += 4) {
        float4 v = *(const float4*)(qp + j);
        qr[j] = v.x; qr[j + 1] = v.y; qr[j + 2] = v.z; qr[j + 3] = v.w;
    }
    float o[64];
#pragma unroll
    for (int j = 0; j < 64; ++j) o[j] = 0.f;
    float m = -1e30f, l = 0.f;

    for (int kt = 0; kt < T_; kt += 16) {
        __syncthreads();
#pragma unroll
        for (int r = 0; r < 16; ++r) {
            size_t base = (size_t)(b * T_ + kt + r) * D_ + h * DH;
            Ks[r][tid] = Kb[base + tid];
            Vs[r][tid] = Vb[base + tid];
        }
        __syncthreads();

        float s[16];
        float tmax = -1e30f;
#pragma unroll
        for (int r = 0; r < 16; ++r) {
            int kg = kt + r;
            float dot = 0.f;
#pragma unroll
            for (int j = 0; j < 64; ++j) dot += qr[j] * Ks[r][j];
            dot += -slope * fabsf((float)(qg - kg))
                 + (1.f - y_mask[b * T_ + kg]) * (-1e9f);
            s[r] = dot;
            tmax = fmaxf(tmax, dot);
        }
        float mnew = fmaxf(m, tmax);
        float corr = __expf(m - mnew);
        l *= corr;
#pragma unroll
        for (int j = 0; j < 64; ++j) o[j] *= corr;
#pragma unroll
        for (int r = 0; r < 16; ++r) {
            float p = __expf(s[r] - mnew);
            l += p;
#pragma unroll
            for (int j = 0; j < 64; ++j) o[j] += p * Vs[r][j];
        }
        m = mnew;
    }
    float inv = 1.f / l;
    float* op = O + ((size_t)(b * T_ + qg) * D_ + h * DH);
#pragma unroll
    for (int j = 0; j < 64; j += 4) {
        float4 v;
        v.x = o[j] * inv; v.y = o[j + 1] * inv;
        v.z = o[j + 2] * inv; v.w = o[j + 3] * inv;
        *(float4*)(op + j) = v;
    }
}

// ---------------------------------------------------------------------------
// out[b,f,t] = tmp[b*T+t, f] * y_mask[b,t]
// ---------------------------------------------------------------------------
__global__ __launch_bounds__(256)
void outtrans_kernel(const float* __restrict__ tmp, const float* __restrict__ y_mask,
                     float* __restrict__ out)
{
    int e = blockIdx.x * 256 + threadIdx.x;
    if (e >= B_ * NF_ * T_) return;
    int t = e & 1023;
    int f = (e >> 10) % NF_;
    int b = e / (NF_ * T_);
    out[e] = tmp[(size_t)(b * T_ + t) * NF_ + f] * y_mask[b * T_ + t];
}

// ---------------------------------------------------------------------------
extern "C" void kernel_launch(void* const* d_in, const int* in_sizes, int n_in,
                              void* d_out, int out_size, void* d_ws, size_t ws_size,
                              hipStream_t stream)
{
    const float* x          = (const float*)d_in[0];
    const float* mu         = (const float*)d_in[1];
    const int*   tokens     = (const int*)  d_in[2];
    const float* t_in       = (const float*)d_in[3];
    const float* y_mask     = (const float*)d_in[4];
    const float* emb        = (const float*)d_in[5];
    const float* proj_in_w  = (const float*)d_in[6];
    const float* proj_in_b  = (const float*)d_in[7];
    const float* posconv_w  = (const float*)d_in[8];
    const float* posconv_b  = (const float*)d_in[9];
    const float* ln0_g      = (const float*)d_in[10];
    const float* ln0_b      = (const float*)d_in[11];
    const float* qw         = (const float*)d_in[12];
    const float* qb         = (const float*)d_in[13];
    const float* kw         = (const float*)d_in[14];
    const float* kb         = (const float*)d_in[15];
    const float* vw         = (const float*)d_in[16];
    const float* vb         = (const float*)d_in[17];
    const float* ow         = (const float*)d_in[18];
    const float* ob         = (const float*)d_in[19];
    const float* ln1_g      = (const float*)d_in[20];
    const float* ln1_b      = (const float*)d_in[21];
    const float* ffw1       = (const float*)d_in[22];
    const float* ffb1       = (const float*)d_in[23];
    const float* ffw2       = (const float*)d_in[24];
    const float* ffb2       = (const float*)d_in[25];
    const float* ln2_g      = (const float*)d_in[26];
    const float* ln2_b      = (const float*)d_in[27];
    const float* skw        = (const float*)d_in[28];
    const float* skb        = (const float*)d_in[29];
    const float* pow_       = (const float*)d_in[30];
    const float* pob        = (const float*)d_in[31];

    const size_t MD = (size_t)M_ * D_;        // 4 Mi floats
    float* ws    = (float*)d_ws;
    float* hA    = ws;                        // MD
    float* hB    = ws + MD;                   // MD
    float* skips = ws + 2 * MD;               // 4*MD
    float* U     = ws + 6 * MD;               // 4*MD union region
    float* q  = U;
    float* k  = U + MD;
    float* v  = U + 2 * MD;
    float* o  = U + 3 * MD;
    float* ff = U;           // (M, F) = 4*MD
    float* wT = U;           // 2*MD per depth
    float* xin = U;          // M*416

    dim3 gD((D_ + 127) / 128, M_ / 64);
    dim3 gF((F_ + 127) / 128, M_ / 64);
    dim3 gO(1, M_ / 64);

    // stem
    xin_kernel<<<M_, 256, 0, stream>>>(x, mu, tokens, emb, xin);
    gemm_kernel<0><<<gD, 256, 0, stream>>>(xin, nullptr, CIN, proj_in_w, proj_in_b,
                                           nullptr, nullptr, hA, M_, D_, CIN, 1.f);
    temb_kernel<<<M_, 256, 0, stream>>>(hA, t_in, y_mask);

    wtrans_kernel<<<32768, 256, 0, stream>>>(posconv_w, wT, 0);
    conv_kernel<<<dim3(8, 16, 4), 256, 0, stream>>>(hA, hB, wT, posconv_b, y_mask);
    wtrans_kernel<<<32768, 256, 0, stream>>>(posconv_w, wT, 1);
    conv_kernel<<<dim3(8, 16, 4), 256, 0, stream>>>(hB, hA, wT, posconv_b + D_, y_mask);

    ln_kernel<<<M_, 256, 0, stream>>>(hA, ln0_g, ln0_b, nullptr);

    float* h = hA;
    float* hx = hB;
    for (int i = 0; i < L_; ++i) {
        if (i >= L_ / 2) {
            const float* s = skips + (size_t)(7 - i) * MD;
            gemm_kernel<0><<<gD, 256, 0, stream>>>(h, s, D_,
                skw + (size_t)(i - 4) * D_ * 2 * D_, skb + (size_t)(i - 4) * D_,
                nullptr, nullptr, hx, M_, D_, 2 * D_, 1.f);
            float* tmp = h; h = hx; hx = tmp;
        }
        gemm_kernel<0><<<gD, 256, 0, stream>>>(h, nullptr, D_,
            qw + (size_t)i * D_ * D_, qb + (size_t)i * D_,
            nullptr, nullptr, q, M_, D_, D_, 0.125f);
        gemm_kernel<0><<<gD, 256, 0, stream>>>(h, nullptr, D_,
            kw + (size_t)i * D_ * D_, kb + (size_t)i * D_,
            nullptr, nullptr, k, M_, D_, D_, 1.f);
        gemm_kernel<0><<<gD, 256, 0, stream>>>(h, nullptr, D_,
            vw + (size_t)i * D_ * D_, vb + (size_t)i * D_,
            nullptr, nullptr, v, M_, D_, D_, 1.f);
        attn_kernel<<<dim3(T_ / 64, H_, B_), 64, 0, stream>>>(q, k, v, y_mask, o);
        gemm_kernel<0><<<gD, 256, 0, stream>>>(o, nullptr, D_,
            ow + (size_t)i * D_ * D_, ob + (size_t)i * D_,
            h, y_mask, hx, M_, D_, D_, 1.f);
        { float* tmp = h; h = hx; hx = tmp; }
        ln_kernel<<<M_, 256, 0, stream>>>(h, ln1_g + (size_t)i * D_, ln1_b + (size_t)i * D_, nullptr);
        gemm_kernel<1><<<gF, 256, 0, stream>>>(h, nullptr, D_,
            ffw1 + (size_t)i * F_ * D_, ffb1 + (size_t)i * F_,
            nullptr, nullptr, ff, M_, F_, D_, 1.f);
        gemm_kernel<0><<<gD, 256, 0, stream>>>(ff, nullptr, F_,
            ffw2 + (size_t)i * D_ * F_, ffb2 + (size_t)i * D_,
            h, y_mask, hx, M_, D_, F_, 1.f);
        { float* tmp = h; h = hx; hx = tmp; }
        ln_kernel<<<M_, 256, 0, stream>>>(h, ln2_g + (size_t)i * D_, ln2_b + (size_t)i * D_, y_mask);
        if (i < L_ / 2) {
            hipMemcpyAsync(skips + (size_t)i * MD, h, MD * sizeof(float),
                           hipMemcpyDeviceToDevice, stream);
        }
    }

    float* tmp = U;
    gemm_kernel<0><<<gO, 256, 0, stream>>>(h, nullptr, D_, pow_, pob,
                                           nullptr, nullptr, tmp, M_, NF_, D_, 1.f);
    outtrans_kernel<<<(B_ * NF_ * T_ + 255) / 256, 256, 0, stream>>>(tmp, y_mask, (float*)d_out);
}

// Round 2
// 9052.246 us; speedup vs baseline: 4.4732x; 4.4732x over previous
//
#include <hip/hip_runtime.h>
#include <hip/hip_bf16.h>
#include <math.h>
#include <stdint.h>

#define B_ 4
#define T_ 1024
#define D_ 1024
#define H_ 16
#define F_ 4096
#define L_ 8
#define NF_ 80
#define E_ 256
#define KW_ 128
#define G_ 16
#define CIN 416       // 2*NF + E
#define DH 64
#define M_ (B_*T_)    // 4096

typedef __attribute__((ext_vector_type(8))) short short8;
typedef __attribute__((ext_vector_type(8))) unsigned short ushort8;
typedef __attribute__((ext_vector_type(4))) float floatx4;

__device__ __forceinline__ float gelu_f(float x) {
    return 0.5f * x * (1.0f + erff(x * 0.70710678118654752f));
}
__device__ __forceinline__ float b2f(unsigned short u) {
    return __uint_as_float(((unsigned int)u) << 16);
}
__device__ __forceinline__ unsigned short f2b(float x) {
    __hip_bfloat16 h = __float2bfloat16(x);
    return *(unsigned short*)&h;
}

// ---------------------------------------------------------------------------
// fp32 -> bf16 convert, 8 elements per thread (n must be multiple of 8)
// ---------------------------------------------------------------------------
__global__ __launch_bounds__(256)
void f2b_kernel(const float* __restrict__ in, __hip_bfloat16* __restrict__ out, int n8)
{
    int i = blockIdx.x * 256 + threadIdx.x;
    if (i >= n8) return;
    const float4* p = (const float4*)in + (size_t)i * 2;
    float4 a = p[0], b = p[1];
    ushort8 r;
    r[0] = f2b(a.x); r[1] = f2b(a.y); r[2] = f2b(a.z); r[3] = f2b(a.w);
    r[4] = f2b(b.x); r[5] = f2b(b.y); r[6] = f2b(b.z); r[7] = f2b(b.w);
    *(ushort8*)((unsigned short*)out + (size_t)i * 8) = r;
}

// ---------------------------------------------------------------------------
// bf16 MFMA GEMM: C[M,N] = post(A@W^T + bias), A (M,K) bf16 row-major
// (optionally split at K1 between A and A2), W (N,K) bf16 row-major.
// 128x128 tile, BK=32, 4 waves, 16x16x32 MFMA, global_load_lds staging.
// Requires M%128==0, N%128==0, K%32==0.
// OUTMODE: 0 = fp32 only, 1 = bf16 only, 2 = both
// ---------------------------------------------------------------------------
template<int ACT, int OUTMODE>
__global__ __launch_bounds__(256)
void mfma_gemm(const __hip_bfloat16* __restrict__ A, const __hip_bfloat16* __restrict__ A2, int K1,
               const __hip_bfloat16* __restrict__ W, const float* __restrict__ bias,
               const float* __restrict__ resid, const float* __restrict__ rowmask,
               float* __restrict__ Cf, __hip_bfloat16* __restrict__ Cb,
               int M, int N, int K, float post_scale)
{
    __shared__ __align__(16) short As[128 * 32];
    __shared__ __align__(16) short Bs[128 * 32];
    const int tid  = threadIdx.x;
    const int lane = tid & 63;
    const int w    = tid >> 6;
    const int wm   = (w & 1) * 64;
    const int wn   = (w >> 1) * 64;
    const int bm   = blockIdx.y * 128;
    const int bn   = blockIdx.x * 128;
    const int lr   = lane >> 2;        // row within 16-row chunk
    const int lc   = (lane & 3) * 8;   // k-element offset of this lane's 16B
    const int fr   = lane & 15;        // fragment row (m or n)
    const int fk   = (lane >> 4) * 8;  // fragment k offset
    const int K2   = K - K1;

    floatx4 acc[4][4] = {};

    for (int k0 = 0; k0 < K; k0 += 32) {
        const int gk = k0 + lc;
        // stage A tile: wave w covers rows [w*32, w*32+32)
#pragma unroll
        for (int j = 0; j < 2; ++j) {
            const int row  = w * 32 + j * 16;
            const int grow = bm + row + lr;
            const __hip_bfloat16* src = (gk < K1)
                ? (A  + (size_t)grow * K1 + gk)
                : (A2 + (size_t)grow * K2 + (gk - K1));
            __builtin_amdgcn_global_load_lds(
                (__attribute__((address_space(1))) void*)(uintptr_t)src,
                (__attribute__((address_space(3))) void*)(uint32_t)(uintptr_t)&As[row * 32],
                16, 0, 0);
        }
        // stage W tile
#pragma unroll
        for (int j = 0; j < 2; ++j) {
            const int row  = w * 32 + j * 16;
            const int grow = bn + row + lr;
            const __hip_bfloat16* src = W + (size_t)grow * K + gk;
            __builtin_amdgcn_global_load_lds(
                (__attribute__((address_space(1))) void*)(uintptr_t)src,
                (__attribute__((address_space(3))) void*)(uint32_t)(uintptr_t)&Bs[row * 32],
                16, 0, 0);
        }
        __syncthreads();

        short8 af[4], bf[4];
#pragma unroll
        for (int mi = 0; mi < 4; ++mi)
            af[mi] = *(const short8*)&As[(wm + mi * 16 + fr) * 32 + fk];
#pragma unroll
        for (int ni = 0; ni < 4; ++ni)
            bf[ni] = *(const short8*)&Bs[(wn + ni * 16 + fr) * 32 + fk];
#pragma unroll
        for (int mi = 0; mi < 4; ++mi)
#pragma unroll
            for (int ni = 0; ni < 4; ++ni)
                acc[mi][ni] = __builtin_amdgcn_mfma_f32_16x16x32_bf16(
                    af[mi], bf[ni], acc[mi][ni], 0, 0, 0);
        __syncthreads();
    }

    // epilogue: C/D layout col = lane&15, row = (lane>>4)*4 + reg
    const int er = (lane >> 4) * 4;
    const int ec = lane & 15;
#pragma unroll
    for (int ni = 0; ni < 4; ++ni) {
        const int col = bn + wn + ni * 16 + ec;
        const float bsv = bias ? bias[col] : 0.f;
#pragma unroll
        for (int mi = 0; mi < 4; ++mi) {
#pragma unroll
            for (int r = 0; r < 4; ++r) {
                const int row = bm + wm + mi * 16 + er + r;
                float v = (acc[mi][ni][r] + bsv) * post_scale;
                if (ACT == 1) v = gelu_f(v);
                if (resid) v += resid[(size_t)row * N + col];
                if (rowmask) v *= rowmask[row];
                if (OUTMODE == 0 || OUTMODE == 2) Cf[(size_t)row * N + col] = v;
                if (OUTMODE == 1 || OUTMODE == 2) Cb[(size_t)row * N + col] = __float2bfloat16(v);
            }
        }
    }
}

// ---------------------------------------------------------------------------
// Generic fp32 GEMM (kept for proj_out, N=80)
// ---------------------------------------------------------------------------
template<int ACT>
__global__ __launch_bounds__(256)
void gemm_kernel(const float* __restrict__ A, const float* __restrict__ A2, int K1,
                 const float* __restrict__ W, const float* __restrict__ bias,
                 const float* __restrict__ resid, const float* __restrict__ rowmask,
                 float* __restrict__ C, int M, int N, int K, float post_scale)
{
    __shared__ float Asm[16][65];
    __shared__ float Wsm[16][132];
    const int tid = threadIdx.x;
    const int tx = tid & 15;
    const int ty = tid >> 4;
    const int bm = blockIdx.y * 64;
    const int bn = blockIdx.x * 128;
    const int lda2 = K - K1;

    float acc[4][8];
#pragma unroll
    for (int i = 0; i < 4; ++i)
#pragma unroll
        for (int j = 0; j < 8; ++j) acc[i][j] = 0.f;

    for (int k0 = 0; k0 < K; k0 += 16) {
#pragma unroll
        for (int l = 0; l < 4; ++l) {
            int e = tid + l * 256;
            int r = e >> 4, c = e & 15;
            int gm = bm + r, gk = k0 + c;
            float v = 0.f;
            if (gm < M && gk < K) {
                v = (gk < K1) ? A[(size_t)gm * K1 + gk]
                              : A2[(size_t)gm * lda2 + (gk - K1)];
            }
            Asm[c][r] = v;
        }
#pragma unroll
        for (int l = 0; l < 8; ++l) {
            int e = tid + l * 256;
            int r = e >> 4, c = e & 15;
            int gn = bn + r, gk = k0 + c;
            float v = 0.f;
            if (gn < N && gk < K) v = W[(size_t)gn * K + gk];
            Wsm[c][r] = v;
        }
        __syncthreads();
#pragma unroll
        for (int kk = 0; kk < 16; ++kk) {
            float a[4], b0[4], b1[4];
#pragma unroll
            for (int i = 0; i < 4; ++i) a[i] = Asm[kk][ty * 4 + i];
#pragma unroll
            for (int j = 0; j < 4; ++j) b0[j] = Wsm[kk][tx * 4 + j];
#pragma unroll
            for (int j = 0; j < 4; ++j) b1[j] = Wsm[kk][64 + tx * 4 + j];
#pragma unroll
            for (int i = 0; i < 4; ++i) {
#pragma unroll
                for (int j = 0; j < 4; ++j) acc[i][j]     += a[i] * b0[j];
#pragma unroll
                for (int j = 0; j < 4; ++j) acc[i][j + 4] += a[i] * b1[j];
            }
        }
        __syncthreads();
    }

#pragma unroll
    for (int i = 0; i < 4; ++i) {
        int gm = bm + ty * 4 + i;
        if (gm >= M) continue;
        float rm = rowmask ? rowmask[gm] : 1.f;
#pragma unroll
        for (int j = 0; j < 8; ++j) {
            int gn = bn + ((j < 4) ? (tx * 4 + j) : (64 + tx * 4 + (j - 4)));
            if (gn >= N) continue;
            float v = acc[i][j];
            if (bias) v += bias[gn];
            v *= post_scale;
            if (ACT == 1) v = gelu_f(v);
            if (resid) v += resid[(size_t)gm * N + gn];
            v *= rm;
            C[(size_t)gm * N + gn] = v;
        }
    }
}

// ---------------------------------------------------------------------------
// Build xin_bf (M, 416) = [x | mu | embed[tokens]] as bf16
// ---------------------------------------------------------------------------
__global__ __launch_bounds__(256)
void xin_kernel(const float* __restrict__ x, const float* __restrict__ mu,
                const int* __restrict__ tokens, const float* __restrict__ emb,
                __hip_bfloat16* __restrict__ xin)
{
    int m = blockIdx.x;
    int b = m >> 10, tt = m & 1023;
    int tok = tokens[m];
    for (int c = threadIdx.x; c < CIN; c += 256) {
        float v;
        if (c < NF_)            v = x[((size_t)b * NF_ + c) * T_ + tt];
        else if (c < 2 * NF_)   v = mu[((size_t)b * NF_ + (c - NF_)) * T_ + tt];
        else                    v = emb[(size_t)tok * E_ + (c - 2 * NF_)];
        xin[(size_t)m * CIN + c] = __float2bfloat16(v);
    }
}

// ---------------------------------------------------------------------------
__global__ __launch_bounds__(256)
void temb_kernel(float* __restrict__ h, const float* __restrict__ t,
                 const float* __restrict__ y_mask)
{
    int m = blockIdx.x;
    int b = m >> 10;
    int d = threadIdx.x * 4;
    float tb = t[b] * 1000.f;
    float rm = y_mask[m];
    float* p = h + (size_t)m * D_ + d;
    float4 v = *(const float4*)p;
    float out[4] = {v.x, v.y, v.z, v.w};
#pragma unroll
    for (int u = 0; u < 4; ++u) {
        int dd = d + u;
        int j = dd & 511;
        float fr = expf((float)j * (-9.210340371976184f / 511.f));
        float ang = tb * fr;
        float e = (dd < 512) ? sinf(ang) : cosf(ang);
        out[u] = (out[u] + e) * rm;
    }
    float4 o; o.x = out[0]; o.y = out[1]; o.z = out[2]; o.w = out[3];
    *(float4*)p = o;
}

// ---------------------------------------------------------------------------
// Transpose posconv weights (per depth) to wT[k][g][i][dl]
// ---------------------------------------------------------------------------
__global__ __launch_bounds__(256)
void wtrans_kernel(const float* __restrict__ w, float* __restrict__ wT, int dep)
{
    int e = blockIdx.x * 256 + threadIdx.x;
    int dl = e & 63;
    int i  = (e >> 6) & 63;
    int g  = (e >> 12) & 15;
    int k  = e >> 16;
    wT[e] = w[(((size_t)dep * D_ + g * 64 + dl) * 64 + i) * KW_ + k];
}

// ---------------------------------------------------------------------------
// Grouped conv1d (fp32), fused hout = hin + gelu(conv + bias) * y_mask
// ---------------------------------------------------------------------------
__global__ __launch_bounds__(256)
void conv_kernel(const float* __restrict__ hin, float* __restrict__ hout,
                 const float* __restrict__ wT, const float* __restrict__ bias,
                 const float* __restrict__ y_mask)
{
    const int t0 = blockIdx.x * 128;
    const int g  = blockIdx.y;
    const int b  = blockIdx.z;
    const int tid = threadIdx.x;
    const int tx = tid & 15;
    const int ty = tid >> 4;
    __shared__ float slab[64][256];

    for (int e = tid; e < 255 * 64; e += 256) {
        int ts = e >> 6, i = e & 63;
        int tg = t0 - 64 + ts;
        float v = 0.f;
        if (tg >= 0 && tg < T_) v = hin[(size_t)(b * T_ + tg) * D_ + g * 64 + i];
        slab[i][ts] = v;
    }
    __syncthreads();

    float acc[8][4];
#pragma unroll
    for (int mm = 0; mm < 8; ++mm)
#pragma unroll
        for (int c = 0; c < 4; ++c) acc[mm][c] = 0.f;

    for (int k = 0; k < KW_; ++k) {
        const float* wk = wT + ((size_t)k * G_ + g) * 4096;
#pragma unroll 4
        for (int i = 0; i < 64; ++i) {
            float4 wv = *(const float4*)(wk + i * 64 + tx * 4);
            float a[8];
#pragma unroll
            for (int mm = 0; mm < 8; ++mm) a[mm] = slab[i][ty * 8 + mm + k];
#pragma unroll
            for (int mm = 0; mm < 8; ++mm) {
                acc[mm][0] += a[mm] * wv.x;
                acc[mm][1] += a[mm] * wv.y;
                acc[mm][2] += a[mm] * wv.z;
                acc[mm][3] += a[mm] * wv.w;
            }
        }
    }

    int dl = tx * 4;
    float4 bb = *(const float4*)(bias + g * 64 + dl);
#pragma unroll
    for (int mm = 0; mm < 8; ++mm) {
        int tt = t0 + ty * 8 + mm;
        float rm = y_mask[b * T_ + tt];
        int ts = ty * 8 + mm + 64;
        float4 o;
        o.x = slab[dl + 0][ts] + gelu_f(acc[mm][0] + bb.x) * rm;
        o.y = slab[dl + 1][ts] + gelu_f(acc[mm][1] + bb.y) * rm;
        o.z = slab[dl + 2][ts] + gelu_f(acc[mm][2] + bb.z) * rm;
        o.w = slab[dl + 3][ts] + gelu_f(acc[mm][3] + bb.w) * rm;
        *(float4*)(hout + (size_t)(b * T_ + tt) * D_ + g * 64 + dl) = o;
    }
}

// ---------------------------------------------------------------------------
// LayerNorm over D (in-place fp32), optional rowmask, optional bf16 shadow out
// ---------------------------------------------------------------------------
__global__ __launch_bounds__(256)
void ln_kernel(float* __restrict__ X, const float* __restrict__ g,
               const float* __restrict__ bt, const float* __restrict__ rowmask,
               __hip_bfloat16* __restrict__ outbf)
{
    const int m = blockIdx.x;
    const int tid = threadIdx.x;
    const int d = tid * 4;
    float* p = X + (size_t)m * D_ + d;
    float4 v = *(const float4*)p;
    float s  = v.x + v.y + v.z + v.w;
    float s2 = v.x * v.x + v.y * v.y + v.z * v.z + v.w * v.w;
#pragma unroll
    for (int off = 32; off; off >>= 1) {
        s  += __shfl_down(s, off);
        s2 += __shfl_down(s2, off);
    }
    __shared__ float rs[4], rs2[4];
    int wid = tid >> 6;
    if ((tid & 63) == 0) { rs[wid] = s; rs2[wid] = s2; }
    __syncthreads();
    s  = rs[0] + rs[1] + rs[2] + rs[3];
    s2 = rs2[0] + rs2[1] + rs2[2] + rs2[3];
    float mean = s * (1.f / D_);
    float var  = s2 * (1.f / D_) - mean * mean;
    float inv  = rsqrtf(var + 1e-5f);
    float rm = rowmask ? rowmask[m] : 1.f;
    float4 gg = *(const float4*)(g + d);
    float4 bb = *(const float4*)(bt + d);
    float4 o;
    o.x = ((v.x - mean) * inv * gg.x + bb.x) * rm;
    o.y = ((v.y - mean) * inv * gg.y + bb.y) * rm;
    o.z = ((v.z - mean) * inv * gg.z + bb.z) * rm;
    o.w = ((v.w - mean) * inv * gg.w + bb.w) * rm;
    *(float4*)p = o;
    if (outbf) {
        __hip_bfloat16* q = outbf + (size_t)m * D_ + d;
        q[0] = __float2bfloat16(o.x);
        q[1] = __float2bfloat16(o.y);
        q[2] = __float2bfloat16(o.z);
        q[3] = __float2bfloat16(o.w);
    }
}

// ---------------------------------------------------------------------------
// Flash attention v2: 4 lanes per query (16 dims each), 64 queries/block,
// bf16 Q/K/V in, bf16 O out, fp32 math, 64-key LDS tiles.
// ---------------------------------------------------------------------------
__global__ __launch_bounds__(256)
void attn2_kernel(const __hip_bfloat16* __restrict__ Q, const __hip_bfloat16* __restrict__ Kb,
                  const __hip_bfloat16* __restrict__ Vb, const float* __restrict__ y_mask,
                  __hip_bfloat16* __restrict__ O)
{
    const int tid = threadIdx.x;
    const int ql  = tid >> 2;          // query within block
    const int dp  = (tid & 3) * 16;    // dim slice start
    const int qg  = blockIdx.x * 64 + ql;
    const int h   = blockIdx.y;
    const int b   = blockIdx.z;
    const float slope = exp2f(-0.5f * (float)(h + 1));
    __shared__ float Ks[64][68];
    __shared__ float Vs[64][68];

    float qr[16], o[16];
    {
        const ushort4* qp = (const ushort4*)(Q + ((size_t)(b * T_ + qg) * D_ + h * DH + dp));
#pragma unroll
        for (int jj = 0; jj < 4; ++jj) {
            ushort4 u = qp[jj];
            qr[jj * 4 + 0] = b2f(u.x); qr[jj * 4 + 1] = b2f(u.y);
            qr[jj * 4 + 2] = b2f(u.z); qr[jj * 4 + 3] = b2f(u.w);
        }
    }
#pragma unroll
    for (int j = 0; j < 16; ++j) o[j] = 0.f;
    float m = -1e30f, l = 0.f;

    for (int kt = 0; kt < T_; kt += 64) {
        __syncthreads();
        {
            const ushort4* kp = (const ushort4*)(Kb + ((size_t)(b * T_ + kt + ql) * D_ + h * DH + dp));
            const ushort4* vp = (const ushort4*)(Vb + ((size_t)(b * T_ + kt + ql) * D_ + h * DH + dp));
#pragma unroll
            for (int jj = 0; jj < 4; ++jj) {
                ushort4 ku = kp[jj], vu = vp[jj];
                Ks[ql][dp + jj * 4 + 0] = b2f(ku.x); Ks[ql][dp + jj * 4 + 1] = b2f(ku.y);
                Ks[ql][dp + jj * 4 + 2] = b2f(ku.z); Ks[ql][dp + jj * 4 + 3] = b2f(ku.w);
                Vs[ql][dp + jj * 4 + 0] = b2f(vu.x); Vs[ql][dp + jj * 4 + 1] = b2f(vu.y);
                Vs[ql][dp + jj * 4 + 2] = b2f(vu.z); Vs[ql][dp + jj * 4 + 3] = b2f(vu.w);
            }
        }
        __syncthreads();

        for (int c = 0; c < 64; c += 16) {
            float s[16];
            float tmax = -1e30f;
#pragma unroll
            for (int r = 0; r < 16; ++r) {
                int kg = kt + c + r;
                float d = 0.f;
#pragma unroll
                for (int j = 0; j < 16; ++j) d += qr[j] * Ks[c + r][dp + j];
                d += __shfl_xor(d, 1);
                d += __shfl_xor(d, 2);
                d += -slope * fabsf((float)(qg - kg))
                   + (1.f - y_mask[b * T_ + kg]) * (-1e9f);
                s[r] = d;
                tmax = fmaxf(tmax, d);
            }
            float mnew = fmaxf(m, tmax);
            float corr = __expf(m - mnew);
            l *= corr;
#pragma unroll
            for (int j = 0; j < 16; ++j) o[j] *= corr;
#pragma unroll
            for (int r = 0; r < 16; ++r) {
                float p = __expf(s[r] - mnew);
                l += p;
#pragma unroll
                for (int j = 0; j < 16; ++j) o[j] += p * Vs[c + r][dp + j];
            }
            m = mnew;
        }
    }
    float inv = 1.f / l;
    __hip_bfloat16* op = O + ((size_t)(b * T_ + qg) * D_ + h * DH + dp);
#pragma unroll
    for (int j = 0; j < 16; ++j) op[j] = __float2bfloat16(o[j] * inv);
}

// ---------------------------------------------------------------------------
__global__ __launch_bounds__(256)
void outtrans_kernel(const float* __restrict__ tmp, const float* __restrict__ y_mask,
                     float* __restrict__ out)
{
    int e = blockIdx.x * 256 + threadIdx.x;
    if (e >= B_ * NF_ * T_) return;
    int t = e & 1023;
    int f = (e >> 10) % NF_;
    int b = e / (NF_ * T_);
    out[e] = tmp[(size_t)(b * T_ + t) * NF_ + f] * y_mask[b * T_ + t];
}

// ---------------------------------------------------------------------------
static void cvt(const float* w, __hip_bfloat16* dst, size_t n, hipStream_t stream)
{
    int n8 = (int)(n / 8);
    f2b_kernel<<<(n8 + 255) / 256, 256, 0, stream>>>(w, dst, n8);
}

extern "C" void kernel_launch(void* const* d_in, const int* in_sizes, int n_in,
                              void* d_out, int out_size, void* d_ws, size_t ws_size,
                              hipStream_t stream)
{
    const float* x          = (const float*)d_in[0];
    const float* mu         = (const float*)d_in[1];
    const int*   tokens     = (const int*)  d_in[2];
    const float* t_in       = (const float*)d_in[3];
    const float* y_mask     = (const float*)d_in[4];
    const float* emb        = (const float*)d_in[5];
    const float* proj_in_w  = (const float*)d_in[6];
    const float* proj_in_b  = (const float*)d_in[7];
    const float* posconv_w  = (const float*)d_in[8];
    const float* posconv_b  = (const float*)d_in[9];
    const float* ln0_g      = (const float*)d_in[10];
    const float* ln0_b      = (const float*)d_in[11];
    const float* qw         = (const float*)d_in[12];
    const float* qb         = (const float*)d_in[13];
    const float* kw         = (const float*)d_in[14];
    const float* kb         = (const float*)d_in[15];
    const float* vw         = (const float*)d_in[16];
    const float* vb         = (const float*)d_in[17];
    const float* ow         = (const float*)d_in[18];
    const float* ob         = (const float*)d_in[19];
    const float* ln1_g      = (const float*)d_in[20];
    const float* ln1_b      = (const float*)d_in[21];
    const float* ffw1       = (const float*)d_in[22];
    const float* ffb1       = (const float*)d_in[23];
    const float* ffw2       = (const float*)d_in[24];
    const float* ffb2       = (const float*)d_in[25];
    const float* ln2_g      = (const float*)d_in[26];
    const float* ln2_b      = (const float*)d_in[27];
    const float* skw        = (const float*)d_in[28];
    const float* skb        = (const float*)d_in[29];
    const float* pow_       = (const float*)d_in[30];
    const float* pob        = (const float*)d_in[31];

    const size_t MB = (size_t)1 << 20;
    char* wsb = (char*)d_ws;
    float*          hA     = (float*)(wsb + 0);            // 16 MB
    float*          hB     = (float*)(wsb + 16 * MB);      // 16 MB
    __hip_bfloat16* hbfA   = (__hip_bfloat16*)(wsb + 32 * MB);   // 8 MB
    __hip_bfloat16* skipbf = (__hip_bfloat16*)(wsb + 40 * MB);   // 32 MB (4 x 8)
    __hip_bfloat16* q_bf   = (__hip_bfloat16*)(wsb + 72 * MB);   // 8 MB
    __hip_bfloat16* k_bf   = (__hip_bfloat16*)(wsb + 80 * MB);   // 8 MB
    __hip_bfloat16* v_bf   = (__hip_bfloat16*)(wsb + 88 * MB);   // 8 MB
    __hip_bfloat16* o_bf   = (__hip_bfloat16*)(wsb + 96 * MB);   // 8 MB
    __hip_bfloat16* ff_bf  = (__hip_bfloat16*)(wsb + 104 * MB);  // 32 MB
    __hip_bfloat16* wslab  = (__hip_bfloat16*)(wsb + 136 * MB);  // 16 MB
    __hip_bfloat16* hbfB   = (__hip_bfloat16*)(wsb + 152 * MB);  // 8 MB
    // aliases (disjoint lifetimes)
    float*          wT     = (float*)(wsb + 104 * MB);     // 33.6 MB, stem only
    __hip_bfloat16* xin_bf = q_bf;                          // 3.4 MB, stem only
    float*          tmpO   = (float*)(wsb + 72 * MB);      // 1.3 MB, tail only

    const size_t MD = (size_t)M_ * D_;

    dim3 gD(D_ / 128, M_ / 128);   // (8, 32)
    dim3 gF(F_ / 128, M_ / 128);   // (32, 32)

    // ---- stem ----
    xin_kernel<<<M_, 256, 0, stream>>>(x, mu, tokens, emb, xin_bf);
    cvt(proj_in_w, wslab, (size_t)D_ * CIN, stream);
    mfma_gemm<0, 0><<<gD, 256, 0, stream>>>(xin_bf, nullptr, CIN, wslab, proj_in_b,
                                            nullptr, nullptr, hA, nullptr, M_, D_, CIN, 1.f);
    temb_kernel<<<M_, 256, 0, stream>>>(hA, t_in, y_mask);

    wtrans_kernel<<<32768, 256, 0, stream>>>(posconv_w, wT, 0);
    conv_kernel<<<dim3(8, 16, 4), 256, 0, stream>>>(hA, hB, wT, posconv_b, y_mask);
    wtrans_kernel<<<32768, 256, 0, stream>>>(posconv_w, wT, 1);
    conv_kernel<<<dim3(8, 16, 4), 256, 0, stream>>>(hB, hA, wT, posconv_b + D_, y_mask);

    ln_kernel<<<M_, 256, 0, stream>>>(hA, ln0_g, ln0_b, nullptr, hbfA);

    float* h = hA;  float* hx = hB;
    __hip_bfloat16* hbf = hbfA;  __hip_bfloat16* hbf_alt = hbfB;

    for (int i = 0; i < L_; ++i) {
        if (i >= L_ / 2) {
            cvt(skw + (size_t)(i - 4) * D_ * 2 * D_, wslab, (size_t)D_ * 2 * D_, stream);
            mfma_gemm<0, 2><<<gD, 256, 0, stream>>>(hbf, skipbf + (size_t)(7 - i) * MD, D_,
                wslab, skb + (size_t)(i - 4) * D_, nullptr, nullptr,
                hx, hbf_alt, M_, D_, 2 * D_, 1.f);
            { float* t0 = h; h = hx; hx = t0; }
            { __hip_bfloat16* t0 = hbf; hbf = hbf_alt; hbf_alt = t0; }
        }
        cvt(qw + (size_t)i * D_ * D_, wslab, (size_t)D_ * D_, stream);
        mfma_gemm<0, 1><<<gD, 256, 0, stream>>>(hbf, nullptr, D_, wslab, qb + (size_t)i * D_,
            nullptr, nullptr, nullptr, q_bf, M_, D_, D_, 0.125f);
        cvt(kw + (size_t)i * D_ * D_, wslab, (size_t)D_ * D_, stream);
        mfma_gemm<0, 1><<<gD, 256, 0, stream>>>(hbf, nullptr, D_, wslab, kb + (size_t)i * D_,
            nullptr, nullptr, nullptr, k_bf, M_, D_, D_, 1.f);
        cvt(vw + (size_t)i * D_ * D_, wslab, (size_t)D_ * D_, stream);
        mfma_gemm<0, 1><<<gD, 256, 0, stream>>>(hbf, nullptr, D_, wslab, vb + (size_t)i * D_,
            nullptr, nullptr, nullptr, v_bf, M_, D_, D_, 1.f);

        attn2_kernel<<<dim3(T_ / 64, H_, B_), 256, 0, stream>>>(q_bf, k_bf, v_bf, y_mask, o_bf);

        cvt(ow + (size_t)i * D_ * D_, wslab, (size_t)D_ * D_, stream);
        mfma_gemm<0, 0><<<gD, 256, 0, stream>>>(o_bf, nullptr, D_, wslab, ob + (size_t)i * D_,
            h, y_mask, hx, nullptr, M_, D_, D_, 1.f);
        { float* t0 = h; h = hx; hx = t0; }

        ln_kernel<<<M_, 256, 0, stream>>>(h, ln1_g + (size_t)i * D_, ln1_b + (size_t)i * D_,
                                          nullptr, hbf);

        cvt(ffw1 + (size_t)i * F_ * D_, wslab, (size_t)F_ * D_, stream);
        mfma_gemm<1, 1><<<gF, 256, 0, stream>>>(hbf, nullptr, D_, wslab, ffb1 + (size_t)i * F_,
            nullptr, nullptr, nullptr, ff_bf, M_, F_, D_, 1.f);
        cvt(ffw2 + (size_t)i * D_ * F_, wslab, (size_t)D_ * F_, stream);
        mfma_gemm<0, 0><<<gD, 256, 0, stream>>>(ff_bf, nullptr, F_, wslab, ffb2 + (size_t)i * D_,
            h, y_mask, hx, nullptr, M_, D_, F_, 1.f);
        { float* t0 = h; h = hx; hx = t0; }

        ln_kernel<<<M_, 256, 0, stream>>>(h, ln2_g + (size_t)i * D_, ln2_b + (size_t)i * D_,
                                          y_mask, hbf);

        if (i < L_ / 2) {
            hipMemcpyAsync(skipbf + (size_t)i * MD, hbf, MD * sizeof(__hip_bfloat16),
                           hipMemcpyDeviceToDevice, stream);
        }
    }

    gemm_kernel<0><<<dim3(1, M_ / 64), 256, 0, stream>>>(h, nullptr, D_, pow_, pob,
        nullptr, nullptr, tmpO, M_, NF_, D_, 1.f);
    outtrans_kernel<<<(B_ * NF_ * T_ + 255) / 256, 256, 0, stream>>>(tmpO, y_mask, (float*)d_out);
}